// Round 22
// baseline (79.449 us; speedup 1.0000x reference)
//
#include <hip/hip_runtime.h>
#include <hip/hip_fp16.h>

#define H 64
#define NA 65536
#define NB 131072
#define NM 16384
#define NC 2048
#define E_AC 65536
#define E_BC 131072
#define E_MC 16384
#define NE_TOT (E_AC + E_BC + E_MC)

#define CAPA 160
#define CAPB 224
#define CAPM 96
#define SLOTB (NC * CAPA)
#define SLOTM (SLOTB + NC * CAPB)
#define SLOT_TOT (SLOTM + NC * CAPM)

typedef __attribute__((ext_vector_type(8))) short bf16x8;
typedef __attribute__((ext_vector_type(4))) float f32x4;

__device__ __forceinline__ float sigmoidf_(float x) { return 1.0f / (1.0f + __expf(-x)); }
__device__ __forceinline__ float softplusf_(float x) {
    return fmaxf(x, 0.0f) + __logf(1.0f + __expf(-fabsf(x)));
}
__device__ __forceinline__ short bf16_of(float f) {
    union { float f; unsigned u; } v; v.f = f;
    unsigned r = (v.u + 0x7fff + ((v.u >> 16) & 1)) >> 16;  // RNE
    return (short)r;
}

// Column-permuted pack position: actual col c (0..63), part = 0(f)/1(s).
__device__ __forceinline__ size_t pack_pos(int k, int col, int S) {
    int part = col >> 6, c = col & 63;
    int t = (c & 3) + part * 4;
    int lo = c >> 2;
    int sm = k >> 5, q = (k >> 3) & 3, e = k & 7;
    return (size_t)(((t * S + sm) * 64) + q * 16 + lo) * 8 + e;
}

// ================= K0: prep0 — append + packs (300 blocks; cnt zeroed by memset) ======
// [0,104): edge append  [104,152): atom pack  [152,184): motif pack
// [184,280): cell pack  [280,296): bond pack  296: biasA  297: biasM  298: biasB  299: biasC
__global__ __launch_bounds__(256) void prep0_kernel(
    const float* __restrict__ Wa, const float* __restrict__ ba,
    const float* __restrict__ Wb, const float* __restrict__ bb_,
    const float* __restrict__ Wm, const float* __restrict__ bm,
    const float* __restrict__ Wf, const float* __restrict__ bf,
    const float* __restrict__ Ws, const float* __restrict__ bs,
    const int* __restrict__ ea, const int* __restrict__ eb, const int* __restrict__ em,
    short* __restrict__ wpA, short* __restrict__ wpM, short* __restrict__ wpB,
    short* __restrict__ wpC,
    float* __restrict__ biasA, float* __restrict__ biasM, float* __restrict__ biasB,
    float* __restrict__ biasC, int* __restrict__ cnt, int* __restrict__ slots)
{
    int b = blockIdx.x, tid = threadIdx.x;
    if (b < 104) {                            // edge append (absolute gAll rows)
        int t0 = b * 256 + tid;
        #pragma unroll
        for (int u2 = 0; u2 < 8; ++u2) {
            int i = t0 + u2 * 26624;
            int r, d, s;
            if (i < E_AC)             { r = 0; s = ea[i];                      d = ea[E_AC + i]; }
            else if (i < E_AC + E_BC) { int k = i - E_AC; r = 1; s = NA + eb[k]; d = eb[E_BC + k]; }
            else                      { int k = i - E_AC - E_BC; r = 2; s = NA + NB + em[k]; d = em[E_MC + k]; }
            int pos = atomicAdd(&cnt[r * NC + d], 1);
            int base, cap;
            if (r == 0)      { base = d * CAPA;         cap = CAPA; }
            else if (r == 1) { base = SLOTB + d * CAPB; cap = CAPB; }
            else             { base = SLOTM + d * CAPM; cap = CAPM; }
            if (pos < cap) slots[base + pos] = s;
        }
    } else if (b < 152) {                     // atom composite pack: 96x128, S=3
        int idx = (b - 104) * 256 + tid;
        int k = idx >> 7, col = idx & 127, c = col & 63;
        const float* WB = ((col < 64) ? Wf : Ws) + (size_t)6 * 2 * H * H + (size_t)H * H;
        float v = 0.0f;
        if (k < 92) {
            const float* a = Wa + (size_t)k * H;
            for (int j = 0; j < H; ++j) v = fmaf(a[j], WB[j * H + c], v);
        }
        wpA[pack_pos(k, col, 3)] = bf16_of(v);
    } else if (b < 184) {                     // motif composite pack: 64x128, S=2
        int idx = (b - 152) * 256 + tid;
        int k = idx >> 7, col = idx & 127, c = col & 63;
        const float* WB = ((col < 64) ? Wf : Ws) + (size_t)8 * 2 * H * H + (size_t)H * H;
        float v = 0.0f;
        if (k < 35) {
            const float* a = Wm + (size_t)k * H;
            for (int j = 0; j < H; ++j) v = fmaf(a[j], WB[j * H + c], v);
        }
        wpM[pack_pos(k, col, 2)] = bf16_of(v);
    } else if (b < 280) {                     // cell top-half relayout: 3 x 64x128, S=2
        int cu = b - 184;
        int rel = cu >> 5;
        int idx = (cu & 31) * 256 + tid;
        int k = idx >> 7, col = idx & 127, c = col & 63;
        float v = ((col < 64) ? Wf : Ws)[(size_t)(6 + rel) * 2 * H * H + (size_t)k * H + c];
        wpC[(size_t)rel * 8192 + pack_pos(k, col, 2)] = bf16_of(v);
    } else if (b < 296) {                     // bond composite pack: 32x128, S=1
        int idx = (b - 280) * 256 + tid;
        int k = idx >> 7, col = idx & 127, c = col & 63;
        const float* WB = ((col < 64) ? Wf : Ws) + (size_t)7 * 2 * H * H + (size_t)H * H;
        float v = 0.0f;
        if (k < 7) {
            const float* a = Wb + (size_t)k * H;
            for (int j = 0; j < H; ++j) v = fmaf(a[j], WB[j * H + c], v);
        }
        wpB[pack_pos(k, col, 1)] = bf16_of(v);
    } else if (b == 296) {
        if (tid < 128) {
            int col = tid, c = col & 63;
            const float* WB = ((col < 64) ? Wf : Ws) + (size_t)6 * 2 * H * H + (size_t)H * H;
            float v = 0.0f;
            for (int j = 0; j < H; ++j) v = fmaf(ba[j], WB[j * H + c], v);
            biasA[col] = v;
        }
    } else if (b == 297) {
        if (tid < 128) {
            int col = tid, c = col & 63;
            const float* WB = ((col < 64) ? Wf : Ws) + (size_t)8 * 2 * H * H + (size_t)H * H;
            float v = 0.0f;
            for (int j = 0; j < H; ++j) v = fmaf(bm[j], WB[j * H + c], v);
            biasM[col] = v;
        }
    } else if (b == 298) {
        if (tid < 128) {
            int col = tid, c = col & 63;
            const float* WB = ((col < 64) ? Wf : Ws) + (size_t)7 * 2 * H * H + (size_t)H * H;
            float v = 0.0f;
            for (int j = 0; j < H; ++j) v = fmaf(bb_[j], WB[j * H + c], v);
            biasB[col] = v;
        }
    } else {
        for (int i = tid; i < 384; i += 256) {
            int rel = i >> 7, col = i & 127, c = col & 63;
            biasC[rel * 128 + col] = ((col < 64) ? bf : bs)[(6 + rel) * H + c];
        }
    }
}

// ---------------- multi-tile G build: wave holds B-frags, does TILES x 16 rows --------
template<int K, int S, bool VEC, int TILES>
__device__ __forceinline__ void gmfma_multi(
    int blk, const float* __restrict__ x, const short* __restrict__ wp,
    const float* __restrict__ bias, __half2* __restrict__ g)
{
    int l = threadIdx.x & 63;
    int wv = threadIdx.x >> 6;
    int lrow = l & 15, q = l >> 4;
    int tile0 = (blk * 4 + wv) * TILES;

    bf16x8 bfrag[8][S];                       // loaded ONCE, reused TILES times
    #pragma unroll
    for (int t = 0; t < 8; ++t)
        #pragma unroll
        for (int s = 0; s < S; ++s)
            bfrag[t][s] = *(const bf16x8*)(wp + (size_t)((t * S + s) * 64 + l) * 8);

    float bF[4], bS[4];
    #pragma unroll
    for (int t = 0; t < 4; ++t) {
        bF[t] = bias[lrow * 4 + t];           // col c = lrow*4 + t
        bS[t] = bias[64 + lrow * 4 + t];
    }

    for (int tt = 0; tt < TILES; ++tt) {
        int r0 = (tile0 + tt) * 16;
        f32x4 acc[8];
        #pragma unroll
        for (int t = 0; t < 8; ++t) acc[t] = (f32x4){0.f, 0.f, 0.f, 0.f};

        const float* xr = x + (size_t)(r0 + lrow) * K;
        #pragma unroll
        for (int s = 0; s < S; ++s) {
            int kb = s * 32 + q * 8;
            bf16x8 afrag;
            if (VEC && kb + 8 <= K) {
                float4 v0 = *(const float4*)(xr + kb);
                float4 v1 = *(const float4*)(xr + kb + 4);
                afrag[0] = bf16_of(v0.x); afrag[1] = bf16_of(v0.y);
                afrag[2] = bf16_of(v0.z); afrag[3] = bf16_of(v0.w);
                afrag[4] = bf16_of(v1.x); afrag[5] = bf16_of(v1.y);
                afrag[6] = bf16_of(v1.z); afrag[7] = bf16_of(v1.w);
            } else {
                #pragma unroll
                for (int e = 0; e < 8; ++e) {
                    float xv = 0.0f;
                    if (kb + e < K) xv = xr[kb + e];
                    afrag[e] = bf16_of(xv);
                }
            }
            #pragma unroll
            for (int t = 0; t < 8; ++t)
                acc[t] = __builtin_amdgcn_mfma_f32_16x16x32_bf16(afrag, bfrag[t][s], acc[t], 0, 0, 0);
        }

        #pragma unroll
        for (int r = 0; r < 4; ++r) {         // one dwordx4 per row
            __half2 h[4];
            #pragma unroll
            for (int t = 0; t < 4; ++t)
                h[t] = __floats2half2_rn(acc[t][r] + bF[t], acc[t + 4][r] + bS[t]);
            *(float4*)(g + (size_t)(r0 + q * 4 + r) * H + lrow * 4) = *(float4*)h;
        }
    }
}

// ================= K1: work (856 blocks, TILES=4, pure MFMA) =================
// [0,512): bond G  [512,768): atom G  [768,832): motif G  [832,856): cell C (3x8)
__global__ __launch_bounds__(256) void work_kernel(
    const float* __restrict__ xa, const float* __restrict__ xb, const float* __restrict__ xm,
    const float* __restrict__ xc,
    const short* __restrict__ wpA, const float* __restrict__ biasA,
    const short* __restrict__ wpM, const float* __restrict__ biasM,
    const short* __restrict__ wpB, const float* __restrict__ biasB,
    const short* __restrict__ wpC, const float* __restrict__ biasC,
    __half2* __restrict__ gAll, __half2* __restrict__ Ccomb)
{
    int b = blockIdx.x;
    if (b < 512) {
        gmfma_multi<7, 1, false, 4>(b, xb, wpB, biasB, gAll + (size_t)NA * H);
    } else if (b < 768) {
        gmfma_multi<92, 3, true, 4>(b - 512, xa, wpA, biasA, gAll);
    } else if (b < 832) {
        gmfma_multi<35, 2, false, 4>(b - 768, xm, wpM, biasM, gAll + (size_t)(NA + NB) * H);
    } else {
        int cu = b - 832;
        int rel = cu >> 3, blk = cu & 7;
        gmfma_multi<64, 2, true, 4>(blk, xc, wpC + (size_t)rel * 8192, biasC + rel * 128,
                                    Ccomb + (size_t)rel * NC * H);
    }
}

// ================= K2: per-cell accumulate + head (2048 blocks x 256, 4 waves) =========
__global__ __launch_bounds__(256) void cellacc_kernel(
    const __half2* __restrict__ gAll,
    const int* __restrict__ slots, const int* __restrict__ cnt,
    const __half2* __restrict__ Ccomb, const float* __restrict__ xc,
    const float* __restrict__ Wp, const float* __restrict__ bp,
    const float* __restrict__ Wo, const float* __restrict__ bo,
    float* __restrict__ out)
{
    __shared__ int   sL[CAPA + CAPB + CAPM];   // 480 ints
    __shared__ float red[4][H];
    __shared__ float vL[H];
    int d = blockIdx.x;
    int tid = threadIdx.x, lane = tid & 63, wv = tid >> 6;   // 4 waves

    int nA = min(cnt[d], CAPA);
    int nB = min(cnt[NC + d], CAPB);
    int nM = min(cnt[2 * NC + d], CAPM);
    for (int i = tid; i < nA; i += 256) sL[i] = slots[d * CAPA + i];
    for (int i = tid; i < nB; i += 256) sL[nA + i] = slots[SLOTB + d * CAPB + i];
    for (int i = tid; i < nM; i += 256) sL[nA + nB + i] = slots[SLOTM + d * CAPM + i];
    float2 ccA = __half22float2(Ccomb[(size_t)d * H + lane]);
    float2 ccB = __half22float2(Ccomb[(size_t)(NC + d) * H + lane]);
    float2 ccM = __half22float2(Ccomb[(size_t)(2 * NC + d) * H + lane]);
    __syncthreads();

    int ntot = nA + nB + nM, nAB = nA + nB;
    float acc = 0.0f;
    int cs = (ntot + 3) >> 2;                  // contiguous chunk per wave
    int p0 = wv * cs, p1 = min(p0 + cs, ntot);

    for (int p = p0; p < p1; p += 4) {
        float cx[4], cy[4], mk[4]; float2 av[4];
        #pragma unroll
        for (int v = 0; v < 4; ++v) {
            int pc = p + v;
            mk[v] = (pc < p1) ? 1.0f : 0.0f;
            pc = min(pc, ntot - 1);
            int row = sL[pc];
            cx[v] = (pc < nA) ? ccA.x : (pc < nAB) ? ccB.x : ccM.x;
            cy[v] = (pc < nA) ? ccA.y : (pc < nAB) ? ccB.y : ccM.y;
            av[v] = __half22float2(gAll[(size_t)row * H + lane]);
        }
        #pragma unroll
        for (int v = 0; v < 4; ++v)
            acc += mk[v] * (sigmoidf_(cx[v] + av[v].x) * softplusf_(cy[v] + av[v].y));
    }

    red[wv][lane] = acc;
    __syncthreads();
    if (wv == 0) {
        float a = 3.0f * xc[(size_t)d * H + lane]
                + red[0][lane] + red[1][lane] + red[2][lane] + red[3][lane];
        vL[lane] = fmaxf(a, 0.0f);
    }
    __syncthreads();

    // head matvec split over 4 waves
    float aj = (wv == 0) ? bp[lane] : 0.0f;
    #pragma unroll
    for (int kk = 0; kk < 16; ++kk) {
        int k = wv * 16 + kk;
        aj = fmaf(vL[k], Wp[k * H + lane], aj);
    }
    red[wv][lane] = aj;
    __syncthreads();
    if (wv == 0) {
        float ajs = red[0][lane] + red[1][lane] + red[2][lane] + red[3][lane];
        float contrib = softplusf_(ajs) * Wo[lane];
        #pragma unroll
        for (int o = 32; o > 0; o >>= 1) contrib += __shfl_down(contrib, o, 64);
        if (lane == 0) out[d] = contrib + bo[0];
    }
}

extern "C" void kernel_launch(void* const* d_in, const int* in_sizes, int n_in,
                              void* d_out, int out_size, void* d_ws, size_t ws_size,
                              hipStream_t stream)
{
    const float* xa = (const float*)d_in[0];
    const float* xb = (const float*)d_in[1];
    const float* xm = (const float*)d_in[2];
    const float* xc = (const float*)d_in[3];
    const float* Wa = (const float*)d_in[4];
    const float* ba = (const float*)d_in[5];
    const float* Wb = (const float*)d_in[6];
    const float* bb_ = (const float*)d_in[7];
    const float* Wm = (const float*)d_in[8];
    const float* bm = (const float*)d_in[9];
    const float* Wf = (const float*)d_in[10];
    const float* bf = (const float*)d_in[11];
    const float* Ws = (const float*)d_in[12];
    const float* bs = (const float*)d_in[13];
    const float* Wp = (const float*)d_in[14];
    const float* bp = (const float*)d_in[15];
    const float* Wo = (const float*)d_in[16];
    const float* bo = (const float*)d_in[17];
    const int* ea = (const int*)d_in[24];
    const int* eb = (const int*)d_in[25];
    const int* em = (const int*)d_in[26];

    // ---- workspace layout (256B-aligned), ~62 MB ----
    char* base = (char*)d_ws;
    size_t o = 0;
    auto alloc = [&](size_t bytes) { char* r = base + o; o = (o + bytes + 255) & ~(size_t)255; return r; };
    int*     cnt   = (int*)    alloc(3 * NC * sizeof(int));
    int*     slots = (int*)    alloc(SLOT_TOT * sizeof(int));
    short*   wpA   = (short*)  alloc(8 * 3 * 64 * 8 * sizeof(short));
    short*   wpM   = (short*)  alloc(8 * 2 * 64 * 8 * sizeof(short));
    short*   wpB   = (short*)  alloc(8 * 1 * 64 * 8 * sizeof(short));
    short*   wpC   = (short*)  alloc(3 * 8192 * sizeof(short));
    float*   biasA = (float*)  alloc(128 * sizeof(float));
    float*   biasM = (float*)  alloc(128 * sizeof(float));
    float*   biasB = (float*)  alloc(128 * sizeof(float));
    float*   biasC = (float*)  alloc(384 * sizeof(float));
    __half2* Ccomb = (__half2*)alloc((size_t)3 * NC * H * sizeof(__half2));
    __half2* gAll  = (__half2*)alloc((size_t)(NA + NB + NM) * H * sizeof(__half2));  // 54.5 MB
    float*   out   = (float*)d_out;

    hipMemsetAsync(cnt, 0, 3 * NC * sizeof(int), stream);
    prep0_kernel<<<300, 256, 0, stream>>>(Wa, ba, Wb, bb_, Wm, bm, Wf, bf, Ws, bs,
                                          ea, eb, em,
                                          wpA, wpM, wpB, wpC,
                                          biasA, biasM, biasB, biasC, cnt, slots);
    work_kernel<<<856, 256, 0, stream>>>(xa, xb, xm, xc,
                                         wpA, biasA, wpM, biasM, wpB, biasB, wpC, biasC,
                                         gAll, Ccomb);
    cellacc_kernel<<<NC, 256, 0, stream>>>(gAll, slots, cnt, Ccomb,
                                           xc, Wp, bp, Wo, bo, out);
}

// Round 23
// 64.230 us; speedup vs baseline: 1.2370x; 1.2370x over previous
//
#include <hip/hip_runtime.h>
#include <hip/hip_fp16.h>

#define H 64
#define NA 65536
#define NB 131072
#define NM 16384
#define NC 2048
#define E_AC 65536
#define E_BC 131072
#define E_MC 16384
#define NE_TOT (E_AC + E_BC + E_MC)

#define CAPA 160
#define CAPB 224
#define CAPM 96
#define SLOTB (NC * CAPA)
#define SLOTM (SLOTB + NC * CAPB)
#define SLOT_TOT (SLOTM + NC * CAPM)

typedef __attribute__((ext_vector_type(8))) short bf16x8;
typedef __attribute__((ext_vector_type(4))) float f32x4;

__device__ __forceinline__ float sigmoidf_(float x) { return 1.0f / (1.0f + __expf(-x)); }
__device__ __forceinline__ float softplusf_(float x) {
    return fmaxf(x, 0.0f) + __logf(1.0f + __expf(-fabsf(x)));
}
__device__ __forceinline__ short bf16_of(float f) {
    union { float f; unsigned u; } v; v.f = f;
    unsigned r = (v.u + 0x7fff + ((v.u >> 16) & 1)) >> 16;  // RNE
    return (short)r;
}

// Column-permuted pack position: actual col c (0..63), part = 0(f)/1(s).
__device__ __forceinline__ size_t pack_pos(int k, int col, int S) {
    int part = col >> 6, c = col & 63;
    int t = (c & 3) + part * 4;
    int lo = c >> 2;
    int sm = k >> 5, q = (k >> 3) & 3, e = k & 7;
    return (size_t)(((t * S + sm) * 64) + q * 16 + lo) * 8 + e;
}

// ================= K0: prep0 — zero cnt + weight packs (196 blocks) =================
__global__ __launch_bounds__(256) void prep0_kernel(
    const float* __restrict__ Wa, const float* __restrict__ ba,
    const float* __restrict__ Wb, const float* __restrict__ bb_,
    const float* __restrict__ Wm, const float* __restrict__ bm,
    const float* __restrict__ Wf, const float* __restrict__ bf,
    const float* __restrict__ Ws, const float* __restrict__ bs,
    short* __restrict__ wpA, short* __restrict__ wpM, short* __restrict__ wpB,
    short* __restrict__ wpC,
    float* __restrict__ biasA, float* __restrict__ biasM, float* __restrict__ biasB,
    float* __restrict__ biasC, int* __restrict__ cnt)
{
    int b = blockIdx.x, tid = threadIdx.x;
    for (int i = b * 256 + tid; i < 3 * NC; i += gridDim.x * 256) cnt[i] = 0;

    if (b < 48) {                             // atom composite pack: 96x128, S=3
        int idx = b * 256 + tid;
        int k = idx >> 7, col = idx & 127, c = col & 63;
        const float* WB = ((col < 64) ? Wf : Ws) + (size_t)6 * 2 * H * H + (size_t)H * H;
        float v = 0.0f;
        if (k < 92) {
            const float* a = Wa + (size_t)k * H;
            for (int j = 0; j < H; ++j) v = fmaf(a[j], WB[j * H + c], v);
        }
        wpA[pack_pos(k, col, 3)] = bf16_of(v);
    } else if (b < 80) {                      // motif composite pack: 64x128, S=2
        int idx = (b - 48) * 256 + tid;
        int k = idx >> 7, col = idx & 127, c = col & 63;
        const float* WB = ((col < 64) ? Wf : Ws) + (size_t)8 * 2 * H * H + (size_t)H * H;
        float v = 0.0f;
        if (k < 35) {
            const float* a = Wm + (size_t)k * H;
            for (int j = 0; j < H; ++j) v = fmaf(a[j], WB[j * H + c], v);
        }
        wpM[pack_pos(k, col, 2)] = bf16_of(v);
    } else if (b < 176) {                     // cell top-half relayout: 3 x 64x128, S=2
        int cu = b - 80;
        int rel = cu >> 5;
        int idx = (cu & 31) * 256 + tid;
        int k = idx >> 7, col = idx & 127, c = col & 63;
        float v = ((col < 64) ? Wf : Ws)[(size_t)(6 + rel) * 2 * H * H + (size_t)k * H + c];
        wpC[(size_t)rel * 8192 + pack_pos(k, col, 2)] = bf16_of(v);
    } else if (b < 192) {                     // bond composite pack: 32x128, S=1
        int idx = (b - 176) * 256 + tid;
        int k = idx >> 7, col = idx & 127, c = col & 63;
        const float* WB = ((col < 64) ? Wf : Ws) + (size_t)7 * 2 * H * H + (size_t)H * H;
        float v = 0.0f;
        if (k < 7) {
            const float* a = Wb + (size_t)k * H;
            for (int j = 0; j < H; ++j) v = fmaf(a[j], WB[j * H + c], v);
        }
        wpB[pack_pos(k, col, 1)] = bf16_of(v);
    } else if (b == 192) {
        if (tid < 128) {
            int col = tid, c = col & 63;
            const float* WB = ((col < 64) ? Wf : Ws) + (size_t)6 * 2 * H * H + (size_t)H * H;
            float v = 0.0f;
            for (int j = 0; j < H; ++j) v = fmaf(ba[j], WB[j * H + c], v);
            biasA[col] = v;
        }
    } else if (b == 193) {
        if (tid < 128) {
            int col = tid, c = col & 63;
            const float* WB = ((col < 64) ? Wf : Ws) + (size_t)8 * 2 * H * H + (size_t)H * H;
            float v = 0.0f;
            for (int j = 0; j < H; ++j) v = fmaf(bm[j], WB[j * H + c], v);
            biasM[col] = v;
        }
    } else if (b == 194) {
        if (tid < 128) {
            int col = tid, c = col & 63;
            const float* WB = ((col < 64) ? Wf : Ws) + (size_t)7 * 2 * H * H + (size_t)H * H;
            float v = 0.0f;
            for (int j = 0; j < H; ++j) v = fmaf(bb_[j], WB[j * H + c], v);
            biasB[col] = v;
        }
    } else {
        for (int i = tid; i < 384; i += 256) {
            int rel = i >> 7, col = i & 127, c = col & 63;
            biasC[rel * 128 + col] = ((col < 64) ? bf : bs)[(6 + rel) * H + c];
        }
    }
}

// ---------------- multi-tile G build: wave holds B-frags, does TILES x 16 rows --------
template<int K, int S, bool VEC, int TILES>
__device__ __forceinline__ void gmfma_multi(
    int blk, const float* __restrict__ x, const short* __restrict__ wp,
    const float* __restrict__ bias, __half2* __restrict__ g)
{
    int l = threadIdx.x & 63;
    int wv = threadIdx.x >> 6;
    int lrow = l & 15, q = l >> 4;
    int tile0 = (blk * 4 + wv) * TILES;

    bf16x8 bfrag[8][S];                       // loaded ONCE, reused TILES times
    #pragma unroll
    for (int t = 0; t < 8; ++t)
        #pragma unroll
        for (int s = 0; s < S; ++s)
            bfrag[t][s] = *(const bf16x8*)(wp + (size_t)((t * S + s) * 64 + l) * 8);

    float bF[4], bS[4];
    #pragma unroll
    for (int t = 0; t < 4; ++t) {
        bF[t] = bias[lrow * 4 + t];           // col c = lrow*4 + t
        bS[t] = bias[64 + lrow * 4 + t];
    }

    for (int tt = 0; tt < TILES; ++tt) {
        int r0 = (tile0 + tt) * 16;
        f32x4 acc[8];
        #pragma unroll
        for (int t = 0; t < 8; ++t) acc[t] = (f32x4){0.f, 0.f, 0.f, 0.f};

        const float* xr = x + (size_t)(r0 + lrow) * K;
        #pragma unroll
        for (int s = 0; s < S; ++s) {
            int kb = s * 32 + q * 8;
            bf16x8 afrag;
            if (VEC && kb + 8 <= K) {
                float4 v0 = *(const float4*)(xr + kb);
                float4 v1 = *(const float4*)(xr + kb + 4);
                afrag[0] = bf16_of(v0.x); afrag[1] = bf16_of(v0.y);
                afrag[2] = bf16_of(v0.z); afrag[3] = bf16_of(v0.w);
                afrag[4] = bf16_of(v1.x); afrag[5] = bf16_of(v1.y);
                afrag[6] = bf16_of(v1.z); afrag[7] = bf16_of(v1.w);
            } else {
                #pragma unroll
                for (int e = 0; e < 8; ++e) {
                    float xv = 0.0f;
                    if (kb + e < K) xv = xr[kb + e];
                    afrag[e] = bf16_of(xv);
                }
            }
            #pragma unroll
            for (int t = 0; t < 8; ++t)
                acc[t] = __builtin_amdgcn_mfma_f32_16x16x32_bf16(afrag, bfrag[t][s], acc[t], 0, 0, 0);
        }

        #pragma unroll
        for (int r = 0; r < 4; ++r) {         // one dwordx4 per row
            __half2 h[4];
            #pragma unroll
            for (int t = 0; t < 4; ++t)
                h[t] = __floats2half2_rn(acc[t][r] + bF[t], acc[t + 4][r] + bS[t]);
            *(float4*)(g + (size_t)(r0 + q * 4 + r) * H + lrow * 4) = *(float4*)h;
        }
    }
}

// ================= K1: work (960 blocks, TILES=4, append FIRST) =================
// [0,104): append  [104,616): bond G  [616,872): atom G  [872,936): motif G
// [936,960): cell C (8 blocks per rel)
__global__ __launch_bounds__(256) void work_kernel(
    const float* __restrict__ xa, const float* __restrict__ xb, const float* __restrict__ xm,
    const float* __restrict__ xc,
    const short* __restrict__ wpA, const float* __restrict__ biasA,
    const short* __restrict__ wpM, const float* __restrict__ biasM,
    const short* __restrict__ wpB, const float* __restrict__ biasB,
    const short* __restrict__ wpC, const float* __restrict__ biasC,
    const int* __restrict__ ea, const int* __restrict__ eb, const int* __restrict__ em,
    int* __restrict__ cnt, int* __restrict__ slots,
    __half2* __restrict__ gAll, __half2* __restrict__ Ccomb)
{
    int b = blockIdx.x, tid = threadIdx.x;
    if (b < 104) {                               // edge append (absolute gAll rows baked in)
        int t0 = b * 256 + tid;
        #pragma unroll
        for (int u2 = 0; u2 < 8; ++u2) {
            int i = t0 + u2 * 26624;
            int r, d, s;
            if (i < E_AC)             { r = 0; s = ea[i];                      d = ea[E_AC + i]; }
            else if (i < E_AC + E_BC) { int k = i - E_AC; r = 1; s = NA + eb[k]; d = eb[E_BC + k]; }
            else                      { int k = i - E_AC - E_BC; r = 2; s = NA + NB + em[k]; d = em[E_MC + k]; }
            int pos = atomicAdd(&cnt[r * NC + d], 1);
            int base, cap;
            if (r == 0)      { base = d * CAPA;         cap = CAPA; }
            else if (r == 1) { base = SLOTB + d * CAPB; cap = CAPB; }
            else             { base = SLOTM + d * CAPM; cap = CAPM; }
            if (pos < cap) slots[base + pos] = s;
        }
    } else if (b < 616) {
        gmfma_multi<7, 1, false, 4>(b - 104, xb, wpB, biasB, gAll + (size_t)NA * H);
    } else if (b < 872) {
        gmfma_multi<92, 3, true, 4>(b - 616, xa, wpA, biasA, gAll);
    } else if (b < 936) {
        gmfma_multi<35, 2, false, 4>(b - 872, xm, wpM, biasM, gAll + (size_t)(NA + NB) * H);
    } else {
        int cu = b - 936;
        int rel = cu >> 3, blk = cu & 7;
        gmfma_multi<64, 2, true, 4>(blk, xc, wpC + (size_t)rel * 8192, biasC + rel * 128,
                                    Ccomb + (size_t)rel * NC * H);
    }
}

// ================= K2: per-cell accumulate + head (2048 blocks x 256, 4 waves) =========
__global__ __launch_bounds__(256) void cellacc_kernel(
    const __half2* __restrict__ gAll,
    const int* __restrict__ slots, const int* __restrict__ cnt,
    const __half2* __restrict__ Ccomb, const float* __restrict__ xc,
    const float* __restrict__ Wp, const float* __restrict__ bp,
    const float* __restrict__ Wo, const float* __restrict__ bo,
    float* __restrict__ out)
{
    __shared__ int   sL[CAPA + CAPB + CAPM];   // 480 ints
    __shared__ float red[4][H];
    __shared__ float vL[H];
    int d = blockIdx.x;
    int tid = threadIdx.x, lane = tid & 63, wv = tid >> 6;   // 4 waves

    int nA = min(cnt[d], CAPA);
    int nB = min(cnt[NC + d], CAPB);
    int nM = min(cnt[2 * NC + d], CAPM);
    for (int i = tid; i < nA; i += 256) sL[i] = slots[d * CAPA + i];
    for (int i = tid; i < nB; i += 256) sL[nA + i] = slots[SLOTB + d * CAPB + i];
    for (int i = tid; i < nM; i += 256) sL[nA + nB + i] = slots[SLOTM + d * CAPM + i];
    float2 ccA = __half22float2(Ccomb[(size_t)d * H + lane]);
    float2 ccB = __half22float2(Ccomb[(size_t)(NC + d) * H + lane]);
    float2 ccM = __half22float2(Ccomb[(size_t)(2 * NC + d) * H + lane]);
    __syncthreads();

    int ntot = nA + nB + nM, nAB = nA + nB;
    float acc = 0.0f;
    int cs = (ntot + 3) >> 2;                  // contiguous chunk per wave
    int p0 = wv * cs, p1 = min(p0 + cs, ntot);

    for (int p = p0; p < p1; p += 4) {
        float cx[4], cy[4], mk[4]; float2 av[4];
        #pragma unroll
        for (int v = 0; v < 4; ++v) {
            int pc = p + v;
            mk[v] = (pc < p1) ? 1.0f : 0.0f;
            pc = min(pc, ntot - 1);
            int row = sL[pc];
            cx[v] = (pc < nA) ? ccA.x : (pc < nAB) ? ccB.x : ccM.x;
            cy[v] = (pc < nA) ? ccA.y : (pc < nAB) ? ccB.y : ccM.y;
            av[v] = __half22float2(gAll[(size_t)row * H + lane]);
        }
        #pragma unroll
        for (int v = 0; v < 4; ++v)
            acc += mk[v] * (sigmoidf_(cx[v] + av[v].x) * softplusf_(cy[v] + av[v].y));
    }

    red[wv][lane] = acc;
    __syncthreads();
    if (wv == 0) {
        float a = 3.0f * xc[(size_t)d * H + lane]
                + red[0][lane] + red[1][lane] + red[2][lane] + red[3][lane];
        vL[lane] = fmaxf(a, 0.0f);
    }
    __syncthreads();

    // head matvec split over 4 waves: wave wv covers k in [wv*16, wv*16+16)
    float aj = (wv == 0) ? bp[lane] : 0.0f;
    #pragma unroll
    for (int kk = 0; kk < 16; ++kk) {
        int k = wv * 16 + kk;
        aj = fmaf(vL[k], Wp[k * H + lane], aj);
    }
    red[wv][lane] = aj;
    __syncthreads();
    if (wv == 0) {
        float ajs = red[0][lane] + red[1][lane] + red[2][lane] + red[3][lane];
        float contrib = softplusf_(ajs) * Wo[lane];
        #pragma unroll
        for (int o = 32; o > 0; o >>= 1) contrib += __shfl_down(contrib, o, 64);
        if (lane == 0) out[d] = contrib + bo[0];
    }
}

extern "C" void kernel_launch(void* const* d_in, const int* in_sizes, int n_in,
                              void* d_out, int out_size, void* d_ws, size_t ws_size,
                              hipStream_t stream)
{
    const float* xa = (const float*)d_in[0];
    const float* xb = (const float*)d_in[1];
    const float* xm = (const float*)d_in[2];
    const float* xc = (const float*)d_in[3];
    const float* Wa = (const float*)d_in[4];
    const float* ba = (const float*)d_in[5];
    const float* Wb = (const float*)d_in[6];
    const float* bb_ = (const float*)d_in[7];
    const float* Wm = (const float*)d_in[8];
    const float* bm = (const float*)d_in[9];
    const float* Wf = (const float*)d_in[10];
    const float* bf = (const float*)d_in[11];
    const float* Ws = (const float*)d_in[12];
    const float* bs = (const float*)d_in[13];
    const float* Wp = (const float*)d_in[14];
    const float* bp = (const float*)d_in[15];
    const float* Wo = (const float*)d_in[16];
    const float* bo = (const float*)d_in[17];
    const int* ea = (const int*)d_in[24];
    const int* eb = (const int*)d_in[25];
    const int* em = (const int*)d_in[26];

    // ---- workspace layout (256B-aligned), ~62 MB ----
    char* base = (char*)d_ws;
    size_t o = 0;
    auto alloc = [&](size_t bytes) { char* r = base + o; o = (o + bytes + 255) & ~(size_t)255; return r; };
    int*     cnt   = (int*)    alloc(3 * NC * sizeof(int));
    int*     slots = (int*)    alloc(SLOT_TOT * sizeof(int));
    short*   wpA   = (short*)  alloc(8 * 3 * 64 * 8 * sizeof(short));
    short*   wpM   = (short*)  alloc(8 * 2 * 64 * 8 * sizeof(short));
    short*   wpB   = (short*)  alloc(8 * 1 * 64 * 8 * sizeof(short));
    short*   wpC   = (short*)  alloc(3 * 8192 * sizeof(short));
    float*   biasA = (float*)  alloc(128 * sizeof(float));
    float*   biasM = (float*)  alloc(128 * sizeof(float));
    float*   biasB = (float*)  alloc(128 * sizeof(float));
    float*   biasC = (float*)  alloc(384 * sizeof(float));
    __half2* Ccomb = (__half2*)alloc((size_t)3 * NC * H * sizeof(__half2));
    __half2* gAll  = (__half2*)alloc((size_t)(NA + NB + NM) * H * sizeof(__half2));  // 54.5 MB
    float*   out   = (float*)d_out;

    prep0_kernel<<<196, 256, 0, stream>>>(Wa, ba, Wb, bb_, Wm, bm, Wf, bf, Ws, bs,
                                          wpA, wpM, wpB, wpC,
                                          biasA, biasM, biasB, biasC, cnt);
    work_kernel<<<960, 256, 0, stream>>>(xa, xb, xm, xc,
                                         wpA, biasA, wpM, biasM, wpB, biasB, wpC, biasC,
                                         ea, eb, em, cnt, slots, gAll, Ccomb);
    cellacc_kernel<<<NC, 256, 0, stream>>>(gAll, slots, cnt, Ccomb,
                                           xc, Wp, bp, Wo, bo, out);
}